// Round 8
// baseline (569.641 us; speedup 1.0000x reference)
//
#include <hip/hip_runtime.h>
#include <hip/hip_bf16.h>
#include <math.h>

#define N_NODES  8192
#define N_EDGES  49152
#define E_TOT    57344   // edges + self-loops
#define IN_F     128
#define HID      64
#define NH1      64
#define NH2      5
#define OUT_F    32
#define F1       4096    // NH1*HID
#define F2       160     // NH2*OUT_F
#define N_BONDS  64
#define ET       16      // agg1 edge-tile
#define KS2      2       // gemm2 k-split (partial buffers)

typedef short bf16x8 __attribute__((ext_vector_type(8)));
typedef float f32x4  __attribute__((ext_vector_type(4)));

__device__ __forceinline__ float lrelu(float x){ return x > 0.f ? x : 0.2f*x; }

__device__ __forceinline__ unsigned short bf16_rne(float f){
    unsigned u = __float_as_uint(f);
    unsigned r = u + 0x7FFF + ((u >> 16) & 1);
    return (unsigned short)(r >> 16);
}
__device__ __forceinline__ float bf16f(unsigned short h){
    return __uint_as_float((unsigned)h << 16);
}

// ---------------- CSR build (sort edges by dst) ----------------
__global__ void k_init_counts(int* counts){
    int i = blockIdx.x*256 + threadIdx.x;
    if (i < N_NODES) counts[i] = 1;   // self-loop
}
__global__ void k_count(const int* __restrict__ ei, int* counts){
    int i = blockIdx.x*256 + threadIdx.x;
    if (i < N_EDGES) atomicAdd(&counts[ei[N_EDGES + i]], 1);
}
__global__ __launch_bounds__(1024) void k_scan(const int* __restrict__ counts,
                                               int* __restrict__ row_start,
                                               int* __restrict__ cursor){
    __shared__ int sd[1024];
    int t = threadIdx.x;
    int v[8]; int sum = 0;
    #pragma unroll
    for (int i=0;i<8;i++){ v[i] = counts[t*8+i]; sum += v[i]; }
    sd[t] = sum; __syncthreads();
    for (int off=1; off<1024; off<<=1){
        int vv = (t >= off) ? sd[t-off] : 0;
        __syncthreads();
        sd[t] += vv;
        __syncthreads();
    }
    int run = sd[t] - sum;  // exclusive prefix
    #pragma unroll
    for (int i=0;i<8;i++){ row_start[t*8+i] = run; cursor[t*8+i] = run; run += v[i]; }
    if (t == 1023) row_start[N_NODES] = run;
}
__global__ void k_fill(const int* __restrict__ ei, int* cursor, int* __restrict__ csr_src){
    int i = blockIdx.x*256 + threadIdx.x;
    if (i >= E_TOT) return;
    int s, d;
    if (i < N_EDGES){ s = ei[i]; d = ei[N_EDGES + i]; }
    else { s = i - N_EDGES; d = s; }
    int pos = atomicAdd(&cursor[d], 1);
    csr_src[pos] = s;
}

// ---------------- split fp32 -> bf16 hi/lo planes ----------------
__global__ void k_split(const float* __restrict__ in, unsigned short* __restrict__ hi,
                        unsigned short* __restrict__ lo, int n){
    int i = blockIdx.x*256 + threadIdx.x;
    if (i < n){
        float f = in[i];
        unsigned short h = bf16_rne(f);
        hi[i] = h;
        lo[i] = bf16_rne(f - bf16f(h));
    }
}

// ------- attention vectors: vsT[k][h] = sum_c a_s[h,c] * W1[h*64+c, k] -------
__global__ __launch_bounds__(128) void k_attvec(const float* __restrict__ W1,
        const float* __restrict__ a_s, const float* __restrict__ a_d,
        float* __restrict__ vsT, float* __restrict__ vdT){
    int h = blockIdx.x, k = threadIdx.x;
    float s = 0.f, d = 0.f;
    for (int c = 0; c < HID; c++){
        float w = W1[(size_t)(h*HID + c)*IN_F + k];   // 128 lanes: coalesced
        s += a_s[h*HID + c] * w;
        d += a_d[h*HID + c] * w;
    }
    vsT[k*NH1 + h] = s;
    vdT[k*NH1 + h] = d;
}

// ---------- alpha dots from x: as1[n,h] = x[n,:] . vsT[:,h] ------------------
__global__ __launch_bounds__(128) void k_alpha1x(const float* __restrict__ x,
        const float* __restrict__ vsT, const float* __restrict__ vdT,
        float* __restrict__ as1, float* __restrict__ ad1){
    int n = blockIdx.x, t = threadIdx.x;
    __shared__ float xs[IN_F];
    xs[t] = x[(size_t)n*IN_F + t];
    __syncthreads();
    if (t < NH1){
        float s = 0.f, d = 0.f;
        for (int k = 0; k < IN_F; k++){
            float xv = xs[k];
            s += xv * vsT[k*NH1 + t];
            d += xv * vdT[k*NH1 + t];
        }
        as1[n*NH1 + t] = s;
        ad1[n*NH1 + t] = d;
    }
}

// ---------- per-node per-head softmax denominators (once, all 64 heads) ------
__global__ __launch_bounds__(64) void k_dinv(const float* __restrict__ as1,
        const float* __restrict__ ad1, const int* __restrict__ row_start,
        const int* __restrict__ csr_src, float* __restrict__ dinv){
    int n = blockIdx.x, h = threadIdx.x;
    float ad = ad1[n*NH1 + h];
    int e0 = row_start[n], e1 = row_start[n+1];
    float d = 0.f;
    for (int e = e0; e < e1; e++){
        int s = csr_src[e];
        d += expf(lrelu(as1[s*NH1 + h] + ad));
    }
    dinv[n*NH1 + h] = 1.f / d;
}

// ------- GEMM1 chunk (MFMA split-bf16): h1c = x @ Wslice^T, K=128 ------------
// grid (CF/128, 64); 4 waves in 2x2, each 64x64 (4x4 tiles of 16x16).
// All operands L2-resident bf16 planes -> direct global fragment loads, no LDS.
__global__ __launch_bounds__(256) void k_gemm1(const unsigned short* __restrict__ xhi,
        const unsigned short* __restrict__ xlo,
        const unsigned short* __restrict__ w1hi,
        const unsigned short* __restrict__ w1lo,
        float* __restrict__ C, int ldc, int cb){
    int wave = threadIdx.x >> 6, lane = threadIdx.x & 63;
    int wm = wave & 1, wn = wave >> 1;
    int m0  = blockIdx.y*128 + wm*64;
    int n0  = blockIdx.x*128 + wn*64;     // chunk-local col
    int q = lane >> 4, l16 = lane & 15;
    f32x4 acc[4][4] = {};
    #pragma unroll
    for (int ks = 0; ks < 4; ks++){
        int kb = ks*32 + q*8;
        bf16x8 ah[4], al[4], bh[4], bl[4];
        #pragma unroll
        for (int mi=0;mi<4;mi++){
            size_t r = (size_t)(m0 + mi*16 + l16)*IN_F + kb;
            ah[mi] = *(const bf16x8*)(xhi + r);
            al[mi] = *(const bf16x8*)(xlo + r);
        }
        #pragma unroll
        for (int ni=0;ni<4;ni++){
            size_t r = (size_t)(cb + n0 + ni*16 + l16)*IN_F + kb;
            bh[ni] = *(const bf16x8*)(w1hi + r);
            bl[ni] = *(const bf16x8*)(w1lo + r);
        }
        #pragma unroll
        for (int mi=0;mi<4;mi++)
            #pragma unroll
            for (int ni=0;ni<4;ni++){
                acc[mi][ni] = __builtin_amdgcn_mfma_f32_16x16x32_bf16(ah[mi], bh[ni], acc[mi][ni], 0,0,0);
                acc[mi][ni] = __builtin_amdgcn_mfma_f32_16x16x32_bf16(ah[mi], bl[ni], acc[mi][ni], 0,0,0);
                acc[mi][ni] = __builtin_amdgcn_mfma_f32_16x16x32_bf16(al[mi], bh[ni], acc[mi][ni], 0,0,0);
            }
    }
    #pragma unroll
    for (int mi=0;mi<4;mi++)
        #pragma unroll
        for (int ni=0;ni<4;ni++)
            #pragma unroll
            for (int i=0;i<4;i++)
                C[(size_t)(m0 + mi*16 + q*4 + i)*ldc + n0 + ni*16 + l16] = acc[mi][ni][i];
}

// ------- layer-1 chunk: softmax-weighted aggregation + bias + ELU ------------
// Emits x1 as split bf16 hi/lo planes (MFMA-ready for gemm2, no conversion there).
__global__ __launch_bounds__(256) void k_agg1(const float* __restrict__ h1c,
        const float* __restrict__ as1, const float* __restrict__ ad1,
        const float* __restrict__ dinv,
        const int* __restrict__ row_start, const int* __restrict__ csr_src,
        const float* __restrict__ b1w,
        unsigned short* __restrict__ x1hi, unsigned short* __restrict__ x1lo,
        int CF, int h0, int chs){
    int n = blockIdx.x, t = threadIdx.x;
    int CHc = 1 << chs;
    __shared__ float ad_s[NH1], dv_s[NH1];
    __shared__ float wt[ET][NH1];
    __shared__ int   st[ET];
    int e0 = row_start[n], e1 = row_start[n+1];
    if (t < CHc){
        ad_s[t] = ad1[n*NH1 + h0 + t];
        dv_s[t] = dinv[n*NH1 + h0 + t];
    }
    __syncthreads();
    int hl = t >> 3;
    float acc[8] = {};
    for (int eb = e0; eb < e1; eb += ET){
        int ne = min(ET, e1 - eb);
        for (int idx = t; idx < ne*CHc; idx += blockDim.x){
            int el = idx >> chs, hh = idx & (CHc-1);
            int s = csr_src[eb + el];
            if (hh == 0) st[el] = s;
            wt[el][hh] = expf(lrelu(as1[s*NH1 + h0 + hh] + ad_s[hh])) * dv_s[hh];
        }
        __syncthreads();
        for (int e = 0; e < ne; e++){
            int s = st[e];
            float w = wt[e][hl];
            float4 v0 = *(const float4*)(h1c + (size_t)s*CF + t*8);
            float4 v1 = *(const float4*)(h1c + (size_t)s*CF + t*8 + 4);
            acc[0] += w*v0.x; acc[1] += w*v0.y; acc[2] += w*v0.z; acc[3] += w*v0.w;
            acc[4] += w*v1.x; acc[5] += w*v1.y; acc[6] += w*v1.z; acc[7] += w*v1.w;
        }
        __syncthreads();
    }
    float4 b0 = *(const float4*)(b1w + t*8);
    float4 b1 = *(const float4*)(b1w + t*8 + 4);
    float v[8] = {acc[0]+b0.x, acc[1]+b0.y, acc[2]+b0.z, acc[3]+b0.w,
                  acc[4]+b1.x, acc[5]+b1.y, acc[6]+b1.z, acc[7]+b1.w};
    bf16x8 hv, lv;
    #pragma unroll
    for (int i=0;i<8;i++){
        float o = v[i] > 0.f ? v[i] : expm1f(v[i]);
        unsigned short h = bf16_rne(o);
        hv[i] = (short)h;
        lv[i] = (short)bf16_rne(o - bf16f(h));
    }
    *(bf16x8*)(x1hi + (size_t)n*CF + t*8) = hv;
    *(bf16x8*)(x1lo + (size_t)n*CF + t*8) = lv;
}

// ---------------- zero partials ----------------
__global__ void k_zero(float4* p){
    p[blockIdx.x*256 + threadIdx.x] = float4{0.f,0.f,0.f,0.f};
}

// ------- GEMM2 chunk (MFMA split-bf16): partial[ks] += x1c @ Wslice^T --------
// grid (512, KS2), 128-thr blocks = 2 waves; each wave: 16-row strip x 80 cols
// (5 n-tiles); sibling wave shares A-fragment addresses -> L1 hits.
// Pure bf16x8 loads (x1 pre-split by agg1), A prefetched across k-steps.
__global__ __launch_bounds__(128) void k_gemm2(const unsigned short* __restrict__ x1hi,
        const unsigned short* __restrict__ x1lo,
        const unsigned short* __restrict__ w2hi,
        const unsigned short* __restrict__ w2lo,
        float* __restrict__ P, int CF, int cb){
    int wv = threadIdx.x >> 6, lane = threadIdx.x & 63;
    int q = lane >> 4, l16 = lane & 15;
    int m0 = blockIdx.x * 16;
    int ks = blockIdx.y;
    int kb0 = ks * (CF/KS2);
    int nk = (CF/KS2)/32;
    size_t arow = (size_t)(m0 + l16)*CF;
    f32x4 acc[5] = {};
    bf16x8 ah = *(const bf16x8*)(x1hi + arow + kb0 + q*8);
    bf16x8 al = *(const bf16x8*)(x1lo + arow + kb0 + q*8);
    for (int t = 0; t < nk; t++){
        int kb = kb0 + t*32 + q*8;
        bf16x8 cah = ah, cal = al;
        if (t + 1 < nk){
            ah = *(const bf16x8*)(x1hi + arow + kb + 32);
            al = *(const bf16x8*)(x1lo + arow + kb + 32);
        }
        #pragma unroll
        for (int ni=0; ni<5; ni++){
            size_t r = (size_t)((wv*5 + ni)*16 + l16)*F1 + cb + kb;
            bf16x8 bh = *(const bf16x8*)(w2hi + r);
            bf16x8 bl = *(const bf16x8*)(w2lo + r);
            acc[ni] = __builtin_amdgcn_mfma_f32_16x16x32_bf16(cah, bh, acc[ni], 0,0,0);
            acc[ni] = __builtin_amdgcn_mfma_f32_16x16x32_bf16(cah, bl, acc[ni], 0,0,0);
            acc[ni] = __builtin_amdgcn_mfma_f32_16x16x32_bf16(cal, bh, acc[ni], 0,0,0);
        }
    }
    float* outp = P + (size_t)ks * N_NODES * F2;
    #pragma unroll
    for (int ni=0; ni<5; ni++)
        #pragma unroll
        for (int i=0;i<4;i++){
            size_t idx = (size_t)(m0 + q*4 + i)*F2 + (wv*5 + ni)*16 + l16;
            outp[idx] += acc[ni][i];   // unique ownership RMW, accumulates chunks
        }
}

// ---------------- reduce KS2 partials -> h2 ----------------
__global__ __launch_bounds__(256) void k_reduce(const float* __restrict__ P,
                                                float* __restrict__ h2){
    const int NV = N_NODES*F2/4;
    int i = blockIdx.x*256 + threadIdx.x;
    float4 a = ((const float4*)P)[i];
    #pragma unroll
    for (int kb = 1; kb < KS2; kb++){
        float4 b = ((const float4*)P)[(size_t)kb*NV + i];
        a.x += b.x; a.y += b.y; a.z += b.z; a.w += b.w;
    }
    ((float4*)h2)[i] = a;
}

// ---------------- attention dots, layer 2 ----------------
__global__ __launch_bounds__(64) void k_alpha2(const float* __restrict__ h2,
        const float* __restrict__ att_s, const float* __restrict__ att_d,
        float* __restrict__ as2, float* __restrict__ ad2){
    int n = blockIdx.x, t = threadIdx.x;
    float ps = 0.f, pd = 0.f;
    if (t < 40){
        float4 h = *(const float4*)(h2 + (size_t)n*F2 + t*4);
        float4 a = ((const float4*)att_s)[t];
        float4 d = ((const float4*)att_d)[t];
        ps = h.x*a.x + h.y*a.y + h.z*a.z + h.w*a.w;
        pd = h.x*d.x + h.y*d.y + h.z*d.z + h.w*d.w;
    }
    ps += __shfl_xor(ps,1); ps += __shfl_xor(ps,2); ps += __shfl_xor(ps,4);
    pd += __shfl_xor(pd,1); pd += __shfl_xor(pd,2); pd += __shfl_xor(pd,4);
    if (t < 40 && (t & 7) == 0){
        as2[n*NH2 + (t>>3)] = ps;
        ad2[n*NH2 + (t>>3)] = pd;
    }
}

// ------- layer-2 softmax + aggregation + head-mean + b2 ----------------------
__global__ __launch_bounds__(256) void k_agg2(const float* __restrict__ h2,
        const float* __restrict__ as2, const float* __restrict__ ad2,
        const int* __restrict__ row_start, const int* __restrict__ csr_src,
        const float* __restrict__ b2, float* __restrict__ x2){
    int n = blockIdx.x, t = threadIdx.x;
    __shared__ float ad_s[NH2], den_s[NH2], sacc[F2];
    int e0 = row_start[n], e1 = row_start[n+1];
    if (t < NH2) ad_s[t] = ad2[n*NH2 + t];
    __syncthreads();
    if (t < NH2){
        float d = 0.f;
        for (int e=e0;e<e1;e++){
            int s = csr_src[e];
            d += expf(lrelu(as2[s*NH2 + t] + ad_s[t]));
        }
        den_s[t] = d;
    }
    __syncthreads();
    if (t < F2){
        int h = t >> 5;
        float adh  = ad_s[h];
        float dinv = 1.f/den_s[h];
        float acc = 0.f;
        for (int e=e0;e<e1;e++){
            int s = csr_src[e];
            float w = expf(lrelu(as2[s*NH2 + h] + adh)) * dinv;
            acc += w * h2[(size_t)s*F2 + t];
        }
        sacc[t] = acc;
    }
    __syncthreads();
    if (t < OUT_F){
        float v = (sacc[t] + sacc[t+32] + sacc[t+64] + sacc[t+96] + sacc[t+128]) * 0.2f + b2[t];
        x2[n*OUT_F + t] = v;
    }
}

// ---------------- bond scores + softmax over 64 bonds ----------------
__global__ __launch_bounds__(64) void k_bond(const float* __restrict__ x2,
        const int* __restrict__ lefts, const int* __restrict__ rights,
        float* __restrict__ out){
    int b = threadIdx.x;
    int L = lefts[b], R = rights[b];
    float s = 0.f;
    #pragma unroll
    for (int c=0;c<OUT_F;c+=4){
        float4 l4 = *(const float4*)(x2 + (size_t)L*OUT_F + c);
        float4 r4 = *(const float4*)(x2 + (size_t)R*OUT_F + c);
        s += l4.x+l4.y+l4.z+l4.w + r4.x+r4.y+r4.z+r4.w;
    }
    float m = s;
    #pragma unroll
    for (int off=1; off<64; off<<=1) m = fmaxf(m, __shfl_xor(m, off));
    float e = expf(s - m);
    float sum = e;
    #pragma unroll
    for (int off=1; off<64; off<<=1) sum += __shfl_xor(sum, off);
    out[b] = e / sum;
}

extern "C" void kernel_launch(void* const* d_in, const int* in_sizes, int n_in,
                              void* d_out, int out_size, void* d_ws, size_t ws_size,
                              hipStream_t stream){
    const float* x      = (const float*)d_in[0];
    const int*   ei     = (const int*)  d_in[1];
    const int*   lefts  = (const int*)  d_in[2];
    const int*   rights = (const int*)  d_in[3];
    const float* W1     = (const float*)d_in[4];
    const float* att_s1 = (const float*)d_in[5];
    const float* att_d1 = (const float*)d_in[6];
    const float* b1     = (const float*)d_in[7];
    const float* W2     = (const float*)d_in[8];
    const float* att_s2 = (const float*)d_in[9];
    const float* att_d2 = (const float*)d_in[10];
    const float* b2     = (const float*)d_in[11];
    float* out = (float*)d_out;

    // ---- choose chunk width from ws_size (same every call) ----
    size_t fixed = (size_t)(KS2*N_NODES*F2 + N_NODES*F2 + 3*N_NODES*NH1
                          + 2*N_NODES*NH2 + N_NODES*OUT_F + 2*IN_F*NH1
                          + 3*N_NODES + 1 + E_TOT) * 4
                 + (size_t)(2*N_NODES*IN_F + 2*F1*IN_F + 2*F2*F1) * 2
                 + 32768;
    int CF = 512;
    const int cands[2] = {2048, 1024};
    for (int c = 0; c < 2; c++){
        // h1c fp32 (CF*4 B/row) + x1 hi/lo planes (CF*2*2 B/row)
        size_t need = fixed + (size_t)N_NODES * cands[c] * 4 * 2;
        if (need <= ws_size){ CF = cands[c]; break; }
    }
    const int NCHUNK = F1 / CF;
    int chs = 0; while ((1 << chs) < CF/HID) chs++;

    char* ws = (char*)d_ws;
    size_t off = 0;
    auto alloc = [&](size_t bytes) -> void* {
        void* p = ws + off;
        off += (bytes + 255) & ~(size_t)255;
        return p;
    };
    float* h1c    = (float*)alloc((size_t)N_NODES*CF*4);
    unsigned short* x1hi = (unsigned short*)alloc((size_t)N_NODES*CF*2);
    unsigned short* x1lo = (unsigned short*)alloc((size_t)N_NODES*CF*2);
    float* part   = (float*)alloc((size_t)KS2*N_NODES*F2*4);
    float* h2     = (float*)alloc((size_t)N_NODES*F2*4);
    float* as1    = (float*)alloc((size_t)N_NODES*NH1*4);
    float* ad1    = (float*)alloc((size_t)N_NODES*NH1*4);
    float* dinv   = (float*)alloc((size_t)N_NODES*NH1*4);
    float* as2    = (float*)alloc((size_t)N_NODES*NH2*4);
    float* ad2    = (float*)alloc((size_t)N_NODES*NH2*4);
    float* x2     = (float*)alloc((size_t)N_NODES*OUT_F*4);
    float* vsT    = (float*)alloc((size_t)IN_F*NH1*4);
    float* vdT    = (float*)alloc((size_t)IN_F*NH1*4);
    unsigned short* xhi  = (unsigned short*)alloc((size_t)N_NODES*IN_F*2);
    unsigned short* xlo  = (unsigned short*)alloc((size_t)N_NODES*IN_F*2);
    unsigned short* w1hi = (unsigned short*)alloc((size_t)F1*IN_F*2);
    unsigned short* w1lo = (unsigned short*)alloc((size_t)F1*IN_F*2);
    unsigned short* w2hi = (unsigned short*)alloc((size_t)F2*F1*2);
    unsigned short* w2lo = (unsigned short*)alloc((size_t)F2*F1*2);
    int* counts    = (int*)alloc((size_t)N_NODES*4);
    int* row_start = (int*)alloc((size_t)(N_NODES+1)*4);
    int* cursor    = (int*)alloc((size_t)N_NODES*4);
    int* csr_src   = (int*)alloc((size_t)E_TOT*4);

    // CSR by destination
    k_init_counts<<<32, 256, 0, stream>>>(counts);
    k_count<<<192, 256, 0, stream>>>(ei, counts);
    k_scan<<<1, 1024, 0, stream>>>(counts, row_start, cursor);
    k_fill<<<224, 256, 0, stream>>>(ei, cursor, csr_src);

    // bf16 hi/lo planes for MFMA operands
    k_split<<<(N_NODES*IN_F+255)/256, 256, 0, stream>>>(x,  xhi,  xlo,  N_NODES*IN_F);
    k_split<<<(F1*IN_F+255)/256,      256, 0, stream>>>(W1, w1hi, w1lo, F1*IN_F);
    k_split<<<(F2*F1+255)/256,        256, 0, stream>>>(W2, w2hi, w2lo, F2*F1);

    // alpha dots + denominators (once, from x)
    k_attvec<<<NH1, 128, 0, stream>>>(W1, att_s1, att_d1, vsT, vdT);
    k_alpha1x<<<N_NODES, 128, 0, stream>>>(x, vsT, vdT, as1, ad1);
    k_dinv<<<N_NODES, 64, 0, stream>>>(as1, ad1, row_start, csr_src, dinv);

    // zero gemm2 partial accumulators
    k_zero<<<KS2*N_NODES*F2/4/256, 256, 0, stream>>>((float4*)part);

    for (int c = 0; c < NCHUNK; c++){
        int cb = c * CF;
        int h0 = cb / HID;
        k_gemm1<<<dim3(CF/128, 64), 256, 0, stream>>>(
            xhi, xlo, w1hi, w1lo, h1c, CF, cb);
        k_agg1<<<N_NODES, CF/8, 0, stream>>>(
            h1c, as1, ad1, dinv, row_start, csr_src, b1 + cb, x1hi, x1lo, CF, h0, chs);
        k_gemm2<<<dim3(512, KS2), 128, 0, stream>>>(
            x1hi, x1lo, w2hi, w2lo, part, CF, cb);
    }

    k_reduce<<<N_NODES*F2/4/256, 256, 0, stream>>>(part, h2);
    k_alpha2<<<N_NODES, 64, 0, stream>>>(h2, att_s2, att_d2, as2, ad2);
    k_agg2<<<N_NODES, 256, 0, stream>>>(h2, as2, ad2, row_start, csr_src, b2, x2);

    k_bond<<<1, 64, 0, stream>>>(x2, lefts, rights, out);
}

// Round 9
// 564.428 us; speedup vs baseline: 1.0092x; 1.0092x over previous
//
#include <hip/hip_runtime.h>
#include <hip/hip_bf16.h>
#include <math.h>

#define N_NODES  8192
#define N_EDGES  49152
#define E_TOT    57344   // edges + self-loops
#define IN_F     128
#define HID      64
#define NH1      64
#define NH2      5
#define OUT_F    32
#define F1       4096    // NH1*HID
#define F2       160     // NH2*OUT_F
#define N_BONDS  64
#define ET       16      // aggx edge-tile
#define KS2      4       // gemm2 k-split (partial buffers)

typedef short bf16x8 __attribute__((ext_vector_type(8)));
typedef float f32x4  __attribute__((ext_vector_type(4)));

__device__ __forceinline__ float lrelu(float x){ return x > 0.f ? x : 0.2f*x; }

__device__ __forceinline__ unsigned short bf16_rne(float f){
    unsigned u = __float_as_uint(f);
    unsigned r = u + 0x7FFF + ((u >> 16) & 1);
    return (unsigned short)(r >> 16);
}
__device__ __forceinline__ float bf16f(unsigned short h){
    return __uint_as_float((unsigned)h << 16);
}

// ---------------- CSR build (sort edges by dst) ----------------
__global__ void k_init_counts(int* counts){
    int i = blockIdx.x*256 + threadIdx.x;
    if (i < N_NODES) counts[i] = 1;   // self-loop
}
__global__ void k_count(const int* __restrict__ ei, int* counts){
    int i = blockIdx.x*256 + threadIdx.x;
    if (i < N_EDGES) atomicAdd(&counts[ei[N_EDGES + i]], 1);
}
__global__ __launch_bounds__(1024) void k_scan(const int* __restrict__ counts,
                                               int* __restrict__ row_start,
                                               int* __restrict__ cursor){
    __shared__ int sd[1024];
    int t = threadIdx.x;
    int v[8]; int sum = 0;
    #pragma unroll
    for (int i=0;i<8;i++){ v[i] = counts[t*8+i]; sum += v[i]; }
    sd[t] = sum; __syncthreads();
    for (int off=1; off<1024; off<<=1){
        int vv = (t >= off) ? sd[t-off] : 0;
        __syncthreads();
        sd[t] += vv;
        __syncthreads();
    }
    int run = sd[t] - sum;  // exclusive prefix
    #pragma unroll
    for (int i=0;i<8;i++){ row_start[t*8+i] = run; cursor[t*8+i] = run; run += v[i]; }
    if (t == 1023) row_start[N_NODES] = run;
}
__global__ void k_fill(const int* __restrict__ ei, int* cursor, int* __restrict__ csr_src){
    int i = blockIdx.x*256 + threadIdx.x;
    if (i >= E_TOT) return;
    int s, d;
    if (i < N_EDGES){ s = ei[i]; d = ei[N_EDGES + i]; }
    else { s = i - N_EDGES; d = s; }
    int pos = atomicAdd(&cursor[d], 1);
    csr_src[pos] = s;
}

// ---------------- split fp32 -> bf16 hi/lo planes ----------------
__global__ void k_split(const float* __restrict__ in, unsigned short* __restrict__ hi,
                        unsigned short* __restrict__ lo, int n){
    int i = blockIdx.x*256 + threadIdx.x;
    if (i < n){
        float f = in[i];
        unsigned short h = bf16_rne(f);
        hi[i] = h;
        lo[i] = bf16_rne(f - bf16f(h));
    }
}

// ------- attention vectors: vsT[k][h] = sum_c a_s[h,c] * W1[h*64+c, k] -------
__global__ __launch_bounds__(128) void k_attvec(const float* __restrict__ W1,
        const float* __restrict__ a_s, const float* __restrict__ a_d,
        float* __restrict__ vsT, float* __restrict__ vdT){
    int h = blockIdx.x, k = threadIdx.x;
    float s = 0.f, d = 0.f;
    for (int c = 0; c < HID; c++){
        float w = W1[(size_t)(h*HID + c)*IN_F + k];
        s += a_s[h*HID + c] * w;
        d += a_d[h*HID + c] * w;
    }
    vsT[k*NH1 + h] = s;
    vdT[k*NH1 + h] = d;
}

// ---------- alpha dots from x: as1[n,h] = x[n,:] . vsT[:,h] ------------------
__global__ __launch_bounds__(128) void k_alpha1x(const float* __restrict__ x,
        const float* __restrict__ vsT, const float* __restrict__ vdT,
        float* __restrict__ as1, float* __restrict__ ad1){
    int n = blockIdx.x, t = threadIdx.x;
    __shared__ float xs[IN_F];
    xs[t] = x[(size_t)n*IN_F + t];
    __syncthreads();
    if (t < NH1){
        float s = 0.f, d = 0.f;
        for (int k = 0; k < IN_F; k++){
            float xv = xs[k];
            s += xv * vsT[k*NH1 + t];
            d += xv * vdT[k*NH1 + t];
        }
        as1[n*NH1 + t] = s;
        ad1[n*NH1 + t] = d;
    }
}

// ---------- per-node per-head softmax denominators (once, all 64 heads) ------
__global__ __launch_bounds__(64) void k_dinv(const float* __restrict__ as1,
        const float* __restrict__ ad1, const int* __restrict__ row_start,
        const int* __restrict__ csr_src, float* __restrict__ dinv){
    int n = blockIdx.x, h = threadIdx.x;
    float ad = ad1[n*NH1 + h];
    int e0 = row_start[n], e1 = row_start[n+1];
    float d = 0.f;
    for (int e = e0; e < e1; e++){
        int s = csr_src[e];
        d += expf(lrelu(as1[s*NH1 + h] + ad));
    }
    dinv[n*NH1 + h] = 1.f / d;
}

// ------- x-space aggregation: tx[h][n][0:128] = sum_e w_{e,h0+h} x[src_e] ----
// Aggregation commutes with the W1 projection (linear), so gather in x-space
// (x = 4 MB, L2-resident) instead of h-space (134+ MB). Block per node,
// blockDim = 16*CH: thread -> head h = t>>4, feats f0 = (t&15)*8.
// Output: bf16 hi/lo planes, MFMA-ready for k_gemm1h.
__global__ __launch_bounds__(256) void k_aggx(const float* __restrict__ x,
        const float* __restrict__ as1, const float* __restrict__ ad1,
        const float* __restrict__ dinv,
        const int* __restrict__ row_start, const int* __restrict__ csr_src,
        unsigned short* __restrict__ txhi, unsigned short* __restrict__ txlo,
        int h0, int CH, int chs){
    int n = blockIdx.x, t = threadIdx.x, nt = blockDim.x;
    __shared__ float ad_s[16], dv_s[16];
    __shared__ float wt[ET][16];
    __shared__ int   st[ET];
    __shared__ float xs[ET][IN_F];
    int e0 = row_start[n], e1 = row_start[n+1];
    if (t < CH){
        ad_s[t] = ad1[n*NH1 + h0 + t];
        dv_s[t] = dinv[n*NH1 + h0 + t];
    }
    int h = t >> 4, f0 = (t & 15)*8;
    float acc[8] = {};
    for (int eb = e0; eb < e1; eb += ET){
        int ne = min(ET, e1 - eb);
        if (t < ne) st[t] = csr_src[eb + t];
        __syncthreads();
        for (int idx = t; idx < ne*32; idx += nt){
            int e = idx >> 5, f4 = idx & 31;
            *(float4*)&xs[e][f4*4] = *(const float4*)(x + (size_t)st[e]*IN_F + f4*4);
        }
        for (int idx = t; idx < (ne << chs); idx += nt){
            int e = idx >> chs, hh = idx & (CH-1);
            wt[e][hh] = expf(lrelu(as1[st[e]*NH1 + h0 + hh] + ad_s[hh])) * dv_s[hh];
        }
        __syncthreads();
        for (int e = 0; e < ne; e++){
            float w = wt[e][h];
            #pragma unroll
            for (int j=0;j<8;j++) acc[j] += w * xs[e][f0+j];
        }
        __syncthreads();
    }
    bf16x8 hv, lv;
    #pragma unroll
    for (int j=0;j<8;j++){
        unsigned short hb = bf16_rne(acc[j]);
        hv[j] = (short)hb;
        lv[j] = (short)bf16_rne(acc[j] - bf16f(hb));
    }
    size_t o = ((size_t)h*N_NODES + n)*IN_F + f0;
    *(bf16x8*)(txhi + o) = hv;
    *(bf16x8*)(txlo + o) = lv;
}

// ------- per-head GEMM (MFMA split-bf16) + bias + ELU -> x1 hi/lo ------------
// x1[:, hg*64..+64] = ELU(tx_h @ W1_h^T + b1). grid (64, CH); 4 waves 2x2,
// wave tile 64x32, K=128. Epilogue repacks via LDS for coalesced bf16 writes.
__global__ __launch_bounds__(256) void k_gemm1h(const unsigned short* __restrict__ txhi,
        const unsigned short* __restrict__ txlo,
        const unsigned short* __restrict__ w1hi,
        const unsigned short* __restrict__ w1lo,
        const float* __restrict__ b1,
        unsigned short* __restrict__ x1hi, unsigned short* __restrict__ x1lo,
        int h0, int CH){
    __shared__ unsigned short hs[128][64];
    __shared__ unsigned short ls[128][64];
    int wave = threadIdx.x >> 6, lane = threadIdx.x & 63;
    int wm = wave & 1, wn = wave >> 1;
    int hc = blockIdx.y;          // chunk-local head
    int hg = h0 + hc;             // global head
    int m0 = blockIdx.x * 128;
    int q = lane >> 4, l16 = lane & 15;
    const unsigned short* Ah = txhi + (size_t)hc*N_NODES*IN_F;
    const unsigned short* Al = txlo + (size_t)hc*N_NODES*IN_F;
    f32x4 acc[4][2] = {};
    #pragma unroll
    for (int ks = 0; ks < 4; ks++){
        int kb = ks*32 + q*8;
        bf16x8 ah[4], al[4], bh[2], bl[2];
        #pragma unroll
        for (int mi=0;mi<4;mi++){
            size_t r = (size_t)(m0 + wm*64 + mi*16 + l16)*IN_F + kb;
            ah[mi] = *(const bf16x8*)(Ah + r);
            al[mi] = *(const bf16x8*)(Al + r);
        }
        #pragma unroll
        for (int ni=0;ni<2;ni++){
            size_t r = (size_t)(hg*64 + wn*32 + ni*16 + l16)*IN_F + kb;
            bh[ni] = *(const bf16x8*)(w1hi + r);
            bl[ni] = *(const bf16x8*)(w1lo + r);
        }
        #pragma unroll
        for (int mi=0;mi<4;mi++)
            #pragma unroll
            for (int ni=0;ni<2;ni++){
                acc[mi][ni] = __builtin_amdgcn_mfma_f32_16x16x32_bf16(ah[mi], bh[ni], acc[mi][ni], 0,0,0);
                acc[mi][ni] = __builtin_amdgcn_mfma_f32_16x16x32_bf16(ah[mi], bl[ni], acc[mi][ni], 0,0,0);
                acc[mi][ni] = __builtin_amdgcn_mfma_f32_16x16x32_bf16(al[mi], bh[ni], acc[mi][ni], 0,0,0);
            }
    }
    #pragma unroll
    for (int mi=0;mi<4;mi++)
        #pragma unroll
        for (int ni=0;ni<2;ni++){
            int c = wn*32 + ni*16 + l16;
            float b = b1[hg*64 + c];
            #pragma unroll
            for (int i=0;i<4;i++){
                int rrow = wm*64 + mi*16 + q*4 + i;
                float v = acc[mi][ni][i] + b;
                float o = v > 0.f ? v : expm1f(v);
                unsigned short hb = bf16_rne(o);
                hs[rrow][c] = hb;
                ls[rrow][c] = bf16_rne(o - bf16f(hb));
            }
        }
    __syncthreads();
    int CHF = CH*64;
    for (int idx = threadIdx.x; idx < 128*8; idx += 256){
        int r = idx >> 3, c8 = (idx & 7)*8;
        size_t o = (size_t)(m0 + r)*CHF + hc*64 + c8;
        *(bf16x8*)(x1hi + o) = *(const bf16x8*)&hs[r][c8];
        *(bf16x8*)(x1lo + o) = *(const bf16x8*)&ls[r][c8];
    }
}

// ---------------- zero partials ----------------
__global__ void k_zero(float4* p){
    p[blockIdx.x*256 + threadIdx.x] = float4{0.f,0.f,0.f,0.f};
}

// ------- GEMM2 chunk (MFMA split-bf16): partial[ks] += x1c @ Wslice^T --------
// grid (512, KS2), 128-thr blocks = 2 waves x 5 n-tiles. Full A+B register
// prefetch across k-steps (12 loads stay in flight behind 15 MFMAs).
__global__ __launch_bounds__(128) void k_gemm2(const unsigned short* __restrict__ x1hi,
        const unsigned short* __restrict__ x1lo,
        const unsigned short* __restrict__ w2hi,
        const unsigned short* __restrict__ w2lo,
        float* __restrict__ P, int CF, int cb){
    int wv = threadIdx.x >> 6, lane = threadIdx.x & 63;
    int q = lane >> 4, l16 = lane & 15;
    int m0 = blockIdx.x * 16;
    int ks = blockIdx.y;
    int kb0 = ks * (CF/KS2);
    int nk = (CF/KS2)/32;
    size_t arow = (size_t)(m0 + l16)*CF;
    f32x4 acc[5] = {};
    bf16x8 ah, al, bh[5], bl[5];
    {
        int kb = kb0 + q*8;
        ah = *(const bf16x8*)(x1hi + arow + kb);
        al = *(const bf16x8*)(x1lo + arow + kb);
        #pragma unroll
        for (int ni=0; ni<5; ni++){
            size_t r = (size_t)((wv*5 + ni)*16 + l16)*F1 + cb + kb;
            bh[ni] = *(const bf16x8*)(w2hi + r);
            bl[ni] = *(const bf16x8*)(w2lo + r);
        }
    }
    for (int t = 0; t < nk; t++){
        bf16x8 cah = ah, cal = al, cbh[5], cbl[5];
        #pragma unroll
        for (int ni=0; ni<5; ni++){ cbh[ni] = bh[ni]; cbl[ni] = bl[ni]; }
        if (t + 1 < nk){
            int kb = kb0 + (t+1)*32 + q*8;
            ah = *(const bf16x8*)(x1hi + arow + kb);
            al = *(const bf16x8*)(x1lo + arow + kb);
            #pragma unroll
            for (int ni=0; ni<5; ni++){
                size_t r = (size_t)((wv*5 + ni)*16 + l16)*F1 + cb + kb;
                bh[ni] = *(const bf16x8*)(w2hi + r);
                bl[ni] = *(const bf16x8*)(w2lo + r);
            }
        }
        #pragma unroll
        for (int ni=0; ni<5; ni++){
            acc[ni] = __builtin_amdgcn_mfma_f32_16x16x32_bf16(cah, cbh[ni], acc[ni], 0,0,0);
            acc[ni] = __builtin_amdgcn_mfma_f32_16x16x32_bf16(cah, cbl[ni], acc[ni], 0,0,0);
            acc[ni] = __builtin_amdgcn_mfma_f32_16x16x32_bf16(cal, cbh[ni], acc[ni], 0,0,0);
        }
    }
    float* outp = P + (size_t)ks * N_NODES * F2;
    #pragma unroll
    for (int ni=0; ni<5; ni++)
        #pragma unroll
        for (int i=0;i<4;i++){
            size_t idx = (size_t)(m0 + q*4 + i)*F2 + (wv*5 + ni)*16 + l16;
            outp[idx] += acc[ni][i];   // unique ownership RMW, accumulates chunks
        }
}

// ---------------- reduce KS2 partials -> h2 ----------------
__global__ __launch_bounds__(256) void k_reduce(const float* __restrict__ P,
                                                float* __restrict__ h2){
    const int NV = N_NODES*F2/4;
    int i = blockIdx.x*256 + threadIdx.x;
    float4 a = ((const float4*)P)[i];
    #pragma unroll
    for (int kb = 1; kb < KS2; kb++){
        float4 b = ((const float4*)P)[(size_t)kb*NV + i];
        a.x += b.x; a.y += b.y; a.z += b.z; a.w += b.w;
    }
    ((float4*)h2)[i] = a;
}

// ---------------- attention dots, layer 2 ----------------
__global__ __launch_bounds__(64) void k_alpha2(const float* __restrict__ h2,
        const float* __restrict__ att_s, const float* __restrict__ att_d,
        float* __restrict__ as2, float* __restrict__ ad2){
    int n = blockIdx.x, t = threadIdx.x;
    float ps = 0.f, pd = 0.f;
    if (t < 40){
        float4 h = *(const float4*)(h2 + (size_t)n*F2 + t*4);
        float4 a = ((const float4*)att_s)[t];
        float4 d = ((const float4*)att_d)[t];
        ps = h.x*a.x + h.y*a.y + h.z*a.z + h.w*a.w;
        pd = h.x*d.x + h.y*d.y + h.z*d.z + h.w*d.w;
    }
    ps += __shfl_xor(ps,1); ps += __shfl_xor(ps,2); ps += __shfl_xor(ps,4);
    pd += __shfl_xor(pd,1); pd += __shfl_xor(pd,2); pd += __shfl_xor(pd,4);
    if (t < 40 && (t & 7) == 0){
        as2[n*NH2 + (t>>3)] = ps;
        ad2[n*NH2 + (t>>3)] = pd;
    }
}

// ------- layer-2 softmax + aggregation + head-mean + b2 ----------------------
__global__ __launch_bounds__(256) void k_agg2(const float* __restrict__ h2,
        const float* __restrict__ as2, const float* __restrict__ ad2,
        const int* __restrict__ row_start, const int* __restrict__ csr_src,
        const float* __restrict__ b2, float* __restrict__ x2){
    int n = blockIdx.x, t = threadIdx.x;
    __shared__ float ad_s[NH2], den_s[NH2], sacc[F2];
    int e0 = row_start[n], e1 = row_start[n+1];
    if (t < NH2) ad_s[t] = ad2[n*NH2 + t];
    __syncthreads();
    if (t < NH2){
        float d = 0.f;
        for (int e=e0;e<e1;e++){
            int s = csr_src[e];
            d += expf(lrelu(as2[s*NH2 + t] + ad_s[t]));
        }
        den_s[t] = d;
    }
    __syncthreads();
    if (t < F2){
        int h = t >> 5;
        float adh  = ad_s[h];
        float dinv = 1.f/den_s[h];
        float acc = 0.f;
        for (int e=e0;e<e1;e++){
            int s = csr_src[e];
            float w = expf(lrelu(as2[s*NH2 + h] + adh)) * dinv;
            acc += w * h2[(size_t)s*F2 + t];
        }
        sacc[t] = acc;
    }
    __syncthreads();
    if (t < OUT_F){
        float v = (sacc[t] + sacc[t+32] + sacc[t+64] + sacc[t+96] + sacc[t+128]) * 0.2f + b2[t];
        x2[n*OUT_F + t] = v;
    }
}

// ---------------- bond scores + softmax over 64 bonds ----------------
__global__ __launch_bounds__(64) void k_bond(const float* __restrict__ x2,
        const int* __restrict__ lefts, const int* __restrict__ rights,
        float* __restrict__ out){
    int b = threadIdx.x;
    int L = lefts[b], R = rights[b];
    float s = 0.f;
    #pragma unroll
    for (int c=0;c<OUT_F;c+=4){
        float4 l4 = *(const float4*)(x2 + (size_t)L*OUT_F + c);
        float4 r4 = *(const float4*)(x2 + (size_t)R*OUT_F + c);
        s += l4.x+l4.y+l4.z+l4.w + r4.x+r4.y+r4.z+r4.w;
    }
    float m = s;
    #pragma unroll
    for (int off=1; off<64; off<<=1) m = fmaxf(m, __shfl_xor(m, off));
    float e = expf(s - m);
    float sum = e;
    #pragma unroll
    for (int off=1; off<64; off<<=1) sum += __shfl_xor(sum, off);
    out[b] = e / sum;
}

extern "C" void kernel_launch(void* const* d_in, const int* in_sizes, int n_in,
                              void* d_out, int out_size, void* d_ws, size_t ws_size,
                              hipStream_t stream){
    const float* x      = (const float*)d_in[0];
    const int*   ei     = (const int*)  d_in[1];
    const int*   lefts  = (const int*)  d_in[2];
    const int*   rights = (const int*)  d_in[3];
    const float* W1     = (const float*)d_in[4];
    const float* att_s1 = (const float*)d_in[5];
    const float* att_d1 = (const float*)d_in[6];
    const float* b1     = (const float*)d_in[7];
    const float* W2     = (const float*)d_in[8];
    const float* att_s2 = (const float*)d_in[9];
    const float* att_d2 = (const float*)d_in[10];
    const float* b2     = (const float*)d_in[11];
    float* out = (float*)d_out;

    // ---- choose head-chunk width CH from ws_size (same every call) ----
    size_t fixed = (size_t)(KS2*N_NODES*F2 + N_NODES*F2 + 3*N_NODES*NH1
                          + 2*N_NODES*NH2 + N_NODES*OUT_F + 2*IN_F*NH1
                          + 3*N_NODES + 1 + E_TOT) * 4
                 + (size_t)(2*F1*IN_F + 2*F2*F1) * 2
                 + 32768;
    int CH = 4;
    const int cands[2] = {16, 8};
    for (int c = 0; c < 2; c++){
        // tx planes: CH*N*128*2 B * 2; x1 planes: N*CH*64*2 B * 2
        size_t need = fixed + (size_t)cands[c]*N_NODES*IN_F*4
                            + (size_t)cands[c]*N_NODES*HID*4;
        if (need <= ws_size){ CH = cands[c]; break; }
    }
    const int NCHUNK = NH1 / CH;
    int chs = 0; while ((1 << chs) < CH) chs++;

    char* ws = (char*)d_ws;
    size_t off = 0;
    auto alloc = [&](size_t bytes) -> void* {
        void* p = ws + off;
        off += (bytes + 255) & ~(size_t)255;
        return p;
    };
    unsigned short* txhi = (unsigned short*)alloc((size_t)CH*N_NODES*IN_F*2);
    unsigned short* txlo = (unsigned short*)alloc((size_t)CH*N_NODES*IN_F*2);
    unsigned short* x1hi = (unsigned short*)alloc((size_t)N_NODES*CH*HID*2);
    unsigned short* x1lo = (unsigned short*)alloc((size_t)N_NODES*CH*HID*2);
    float* part   = (float*)alloc((size_t)KS2*N_NODES*F2*4);
    float* h2     = (float*)alloc((size_t)N_NODES*F2*4);
    float* as1    = (float*)alloc((size_t)N_NODES*NH1*4);
    float* ad1    = (float*)alloc((size_t)N_NODES*NH1*4);
    float* dinv   = (float*)alloc((size_t)N_NODES*NH1*4);
    float* as2    = (float*)alloc((size_t)N_NODES*NH2*4);
    float* ad2    = (float*)alloc((size_t)N_NODES*NH2*4);
    float* x2     = (float*)alloc((size_t)N_NODES*OUT_F*4);
    float* vsT    = (float*)alloc((size_t)IN_F*NH1*4);
    float* vdT    = (float*)alloc((size_t)IN_F*NH1*4);
    unsigned short* w1hi = (unsigned short*)alloc((size_t)F1*IN_F*2);
    unsigned short* w1lo = (unsigned short*)alloc((size_t)F1*IN_F*2);
    unsigned short* w2hi = (unsigned short*)alloc((size_t)F2*F1*2);
    unsigned short* w2lo = (unsigned short*)alloc((size_t)F2*F1*2);
    int* counts    = (int*)alloc((size_t)N_NODES*4);
    int* row_start = (int*)alloc((size_t)(N_NODES+1)*4);
    int* cursor    = (int*)alloc((size_t)N_NODES*4);
    int* csr_src   = (int*)alloc((size_t)E_TOT*4);

    // CSR by destination
    k_init_counts<<<32, 256, 0, stream>>>(counts);
    k_count<<<192, 256, 0, stream>>>(ei, counts);
    k_scan<<<1, 1024, 0, stream>>>(counts, row_start, cursor);
    k_fill<<<224, 256, 0, stream>>>(ei, cursor, csr_src);

    // bf16 hi/lo planes for MFMA weight operands
    k_split<<<(F1*IN_F+255)/256, 256, 0, stream>>>(W1, w1hi, w1lo, F1*IN_F);
    k_split<<<(F2*F1+255)/256,   256, 0, stream>>>(W2, w2hi, w2lo, F2*F1);

    // alpha dots + denominators (once, from x)
    k_attvec<<<NH1, 128, 0, stream>>>(W1, att_s1, att_d1, vsT, vdT);
    k_alpha1x<<<N_NODES, 128, 0, stream>>>(x, vsT, vdT, as1, ad1);
    k_dinv<<<N_NODES, 64, 0, stream>>>(as1, ad1, row_start, csr_src, dinv);

    // zero gemm2 partial accumulators
    k_zero<<<KS2*N_NODES*F2/4/256, 256, 0, stream>>>((float4*)part);

    for (int c = 0; c < NCHUNK; c++){
        int h0 = c * CH;
        int CF = CH * HID;
        k_aggx<<<N_NODES, 16*CH, 0, stream>>>(
            x, as1, ad1, dinv, row_start, csr_src, txhi, txlo, h0, CH, chs);
        k_gemm1h<<<dim3(64, CH), 256, 0, stream>>>(
            txhi, txlo, w1hi, w1lo, b1, x1hi, x1lo, h0, CH);
        k_gemm2<<<dim3(512, KS2), 128, 0, stream>>>(
            x1hi, x1lo, w2hi, w2lo, part, CF, h0*HID);
    }

    k_reduce<<<N_NODES*F2/4/256, 256, 0, stream>>>(part, h2);
    k_alpha2<<<N_NODES, 64, 0, stream>>>(h2, att_s2, att_d2, as2, ad2);
    k_agg2<<<N_NODES, 256, 0, stream>>>(h2, as2, ad2, row_start, csr_src, b2, x2);

    k_bond<<<1, 64, 0, stream>>>(x2, lefts, rights, out);
}